// Round 2
// baseline (1543.777 us; speedup 1.0000x reference)
//
#include <hip/hip_runtime.h>
#include <hip/hip_bf16.h>
#include <math.h>

#define C 128
#define HDIM 32

// ---------------- init: zero counters ----------------
__global__ __launch_bounds__(256) void initk(unsigned* cnt, float* colsum, float* pSum, int N) {
    int i = blockIdx.x * 256 + threadIdx.x;
    if (i < N) cnt[i] = 0u;
    if (i < 128) colsum[i] = 0.f;
    if (i == 128) pSum[0] = 0.f;
}

// ---------------- degree count (edge_index is int32!) ----------------
__global__ __launch_bounds__(256) void countk(const int* __restrict__ ei, unsigned* cnt, int E) {
    int e = blockIdx.x * 256 + threadIdx.x;
    if (e < E) atomicAdd(&cnt[ei[E + e]], 1u);
}

// ---------------- dinv = rsqrt(deg+1), in place ----------------
__global__ __launch_bounds__(256) void dinvk(unsigned* cnt, int N) {
    int i = blockIdx.x * 256 + threadIdx.x;
    if (i < N) {
        float d = (float)(cnt[i] + 1u);   // +1 for self loop
        ((float*)cnt)[i] = rsqrtf(d);
    }
}

// ---------------- fused GEMM: hs[i, y*128 + n] = dinv[i] * (x @ W_y)  ----------------
// blockIdx.y = 0 -> aW, 1 -> cW. 128x128 tile, 256 threads, 8x8 per-thread.
__global__ __launch_bounds__(256) void gemmk(const float* __restrict__ x,
                                             const float* __restrict__ aW,
                                             const float* __restrict__ cW,
                                             const float* __restrict__ dinv,
                                             float* __restrict__ hs,
                                             float* __restrict__ agg, int N) {
    __shared__ float As[32][132];   // transposed x tile: As[k][m]
    __shared__ float Bs[32][132];   // W tile: Bs[k][n]
    const float* W = (blockIdx.y == 0) ? aW : cW;
    const int colBase = blockIdx.y * 128;
    const int row0 = blockIdx.x * 128;
    const int t = threadIdx.x;
    const int tx = t & 15, ty = t >> 4;
    float acc[8][8] = {};

    for (int k0 = 0; k0 < C; k0 += 32) {
        // A: 128 rows x 32 k, as 1024 float4
        for (int i = 0; i < 4; ++i) {
            int v = t + i * 256;
            int kq = v & 7, row = v >> 3;
            int grow = row0 + row;
            float4 f = make_float4(0.f, 0.f, 0.f, 0.f);
            if (grow < N) f = *(const float4*)&x[(size_t)grow * C + k0 + kq * 4];
            As[kq * 4 + 0][row] = f.x;
            As[kq * 4 + 1][row] = f.y;
            As[kq * 4 + 2][row] = f.z;
            As[kq * 4 + 3][row] = f.w;
        }
        // B: 32 k x 128 n
        for (int i = 0; i < 4; ++i) {
            int v = t + i * 256;
            int nq = v & 31, kk = v >> 5;
            *(float4*)&Bs[kk][nq * 4] = *(const float4*)&W[(size_t)(k0 + kk) * C + nq * 4];
        }
        __syncthreads();
        for (int kk = 0; kk < 32; ++kk) {
            float a[8], b[8];
            *(float4*)&a[0] = *(float4*)&As[kk][ty * 8];
            *(float4*)&a[4] = *(float4*)&As[kk][ty * 8 + 4];
            *(float4*)&b[0] = *(float4*)&Bs[kk][tx * 8];
            *(float4*)&b[4] = *(float4*)&Bs[kk][tx * 8 + 4];
#pragma unroll
            for (int m = 0; m < 8; ++m)
#pragma unroll
                for (int n = 0; n < 8; ++n) acc[m][n] += a[m] * b[n];
        }
        __syncthreads();
    }
    // epilogue: scale by dinv[row], write hs and agg (agg init = self-loop term)
    for (int m = 0; m < 8; ++m) {
        int grow = row0 + ty * 8 + m;
        if (grow >= N) break;
        float dv = dinv[grow];
        float4 v0, v1;
        v0.x = acc[m][0] * dv; v0.y = acc[m][1] * dv; v0.z = acc[m][2] * dv; v0.w = acc[m][3] * dv;
        v1.x = acc[m][4] * dv; v1.y = acc[m][5] * dv; v1.z = acc[m][6] * dv; v1.w = acc[m][7] * dv;
        size_t base = (size_t)grow * 256 + colBase + tx * 8;
        *(float4*)&hs[base] = v0;
        *(float4*)&hs[base + 4] = v1;
        *(float4*)&agg[base] = v0;
        *(float4*)&agg[base + 4] = v1;
    }
}

// ---------------- edge scatter: one wave per edge, lane l -> features l, l+64, l+128, l+192 ----
__global__ __launch_bounds__(256) void scatterk(const int* __restrict__ ei,
                                                const float* __restrict__ hs,
                                                float* __restrict__ agg, int E) {
    int gtid = blockIdx.x * 256 + threadIdx.x;
    int wave = gtid >> 6;
    int lane = threadIdx.x & 63;
    if (wave >= E) return;
    size_t s = (size_t)(unsigned)ei[wave];
    size_t d = (size_t)(unsigned)ei[E + wave];
    const float* src = &hs[s * 256 + lane];
    float* dst = &agg[d * 256 + lane];
    float v0 = src[0], v1 = src[64], v2 = src[128], v3 = src[192];
    atomicAdd(&dst[0], v0);
    atomicAdd(&dst[64], v1);
    atomicAdd(&dst[128], v2);
    atomicAdd(&dst[192], v3);
}

// ---------------- epilogue: ga = relu(dinv*agg_a + ab) + x ; colsum of critic branch ----------
__global__ __launch_bounds__(256) void epiloguek(const float* __restrict__ agg,
                                                 const float* __restrict__ dinv,
                                                 const float* __restrict__ x,
                                                 const float* __restrict__ ab,
                                                 const float* __restrict__ cb,
                                                 float* __restrict__ ga,
                                                 float* __restrict__ colsum, int N) {
    int t = threadIdx.x;
    float bias = (t < 128) ? ab[t] : cb[t - 128];
    float accc = 0.f;
    int i0 = blockIdx.x * 32;
    for (int n = 0; n < 32; ++n) {
        int i = i0 + n;
        if (i >= N) break;
        float r = dinv[i] * agg[(size_t)i * 256 + t] + bias;
        r = fmaxf(r, 0.f) + x[(size_t)i * C + (t & 127)];
        if (t < 128) ga[(size_t)i * C + t] = r;
        else accc += r;
    }
    if (t >= 128) atomicAdd(&colsum[t - 128], accc);
}

__device__ inline float softplusf(float v) {
    return (v > 20.f) ? v : log1pf(expf(v));
}

// ---------------- actor MLP: 8 nodes per block ----------------
__global__ __launch_bounds__(256) void actork(const float* __restrict__ ga,
                                              const float* __restrict__ a1W, const float* __restrict__ a1b,
                                              const float* __restrict__ a2W, const float* __restrict__ a2b,
                                              const float* __restrict__ a3W, const float* __restrict__ a3b,
                                              float* __restrict__ out, float* __restrict__ pSum, int N) {
    __shared__ float sga[8][132];
    __shared__ float sh1[8][33];
    __shared__ float sh2[8][33];
    __shared__ float sp[8];
    int t = threadIdx.x;
    int i0 = blockIdx.x * 8;
    for (int i = 0; i < 4; ++i) {
        int v = t + i * 256;
        int r = v >> 7, c = v & 127;
        int node = i0 + r;
        sga[r][c] = (node < N) ? ga[(size_t)node * C + c] : 0.f;
    }
    __syncthreads();
    int n = t >> 5, o = t & 31;
    float acc = a1b[o];
#pragma unroll 8
    for (int k = 0; k < 128; ++k) acc += sga[n][k] * a1W[k * 32 + o];
    sh1[n][o] = fmaxf(acc, 0.f);
    __syncthreads();
    acc = a2b[o];
#pragma unroll
    for (int k = 0; k < 32; ++k) acc += sh1[n][k] * a2W[k * 32 + o];
    sh2[n][o] = fmaxf(acc, 0.f);
    __syncthreads();
    if (o < 2) {
        float a = a3b[o];
#pragma unroll
        for (int k = 0; k < 32; ++k) a += sh2[n][k] * a3W[k * 2 + o];
        int node = i0 + n;
        if (node < N) {
            float spv = softplusf(a);
            if (o == 0) out[node] = spv + 1e-20f;
            else { out[(size_t)N + 2 + node] = spv; sp[n] = spv; }
        } else if (o == 1) sp[n] = 0.f;
    }
    __syncthreads();
    if (t == 0) {
        float s = 0.f;
        for (int j = 0; j < 8; ++j) s += sp[j];
        atomicAdd(pSum, s);
    }
}

// ---------------- critic head: colsum[128] -> value[2] ----------------
__global__ void critick(const float* __restrict__ colsum,
                        const float* __restrict__ c1W, const float* __restrict__ c1b,
                        const float* __restrict__ c2W, const float* __restrict__ c2b,
                        const float* __restrict__ c3W, const float* __restrict__ c3b,
                        float* __restrict__ out, int N) {
    __shared__ float s1[32], s2[32];
    int t = threadIdx.x;
    if (t < 32) {
        float acc = c1b[t];
        for (int k = 0; k < 128; ++k) acc += colsum[k] * c1W[k * 32 + t];
        s1[t] = fmaxf(acc, 0.f);
    }
    __syncthreads();
    if (t < 32) {
        float acc = c2b[t];
        for (int k = 0; k < 32; ++k) acc += s1[k] * c2W[k * 32 + t];
        s2[t] = fmaxf(acc, 0.f);
    }
    __syncthreads();
    if (t < 2) {
        float acc = c3b[t];
        for (int k = 0; k < 32; ++k) acc += s2[k] * c3W[k * 2 + t];
        out[(size_t)N + t] = acc;
    }
}

// ---------------- normalize probs ----------------
__global__ __launch_bounds__(256) void normk(float* __restrict__ out, const float* __restrict__ pSum, int N) {
    int i = blockIdx.x * 256 + threadIdx.x;
    if (i < N) out[(size_t)N + 2 + i] /= pSum[0];
}

extern "C" void kernel_launch(void* const* d_in, const int* in_sizes, int n_in,
                              void* d_out, int out_size, void* d_ws, size_t ws_size,
                              hipStream_t stream) {
    const float* x   = (const float*)d_in[0];
    const int* ei    = (const int*)d_in[1];   // int32 per harness convention
    const float* aW  = (const float*)d_in[2];
    const float* ab  = (const float*)d_in[3];
    const float* a1W = (const float*)d_in[4];
    const float* a1b = (const float*)d_in[5];
    const float* a2W = (const float*)d_in[6];
    const float* a2b = (const float*)d_in[7];
    const float* a3W = (const float*)d_in[8];
    const float* a3b = (const float*)d_in[9];
    const float* cW  = (const float*)d_in[10];
    const float* cb  = (const float*)d_in[11];
    const float* c1W = (const float*)d_in[12];
    const float* c1b = (const float*)d_in[13];
    const float* c2W = (const float*)d_in[14];
    const float* c2b = (const float*)d_in[15];
    const float* c3W = (const float*)d_in[16];
    const float* c3b = (const float*)d_in[17];

    const int N = in_sizes[0] / C;
    const int E = in_sizes[1] / 2;
    float* out = (float*)d_out;

    char* ws = (char*)d_ws;
    size_t off = 0;
    auto alloc = [&](size_t bytes) {
        size_t o = off;
        off = (off + bytes + 255) & ~(size_t)255;
        return (void*)(ws + o);
    };
    unsigned* cnt = (unsigned*)alloc((size_t)N * 4);          // becomes dinv (f32) in place
    float* hs     = (float*)alloc((size_t)N * 256 * 4);        // [N][256] scaled h (a|c); becomes ga later
    float* agg    = (float*)alloc((size_t)N * 256 * 4);        // accumulator
    float* colsum = (float*)alloc(128 * 4);
    float* pSum   = (float*)alloc(4);
    float* dinv = (float*)cnt;
    float* ga = hs;  // reuse hs region after scatter completes

    initk<<<(N + 255) / 256, 256, 0, stream>>>(cnt, colsum, pSum, N);
    countk<<<(E + 255) / 256, 256, 0, stream>>>(ei, cnt, E);
    dinvk<<<(N + 255) / 256, 256, 0, stream>>>(cnt, N);
    gemmk<<<dim3((N + 127) / 128, 2), 256, 0, stream>>>(x, aW, cW, dinv, hs, agg, N);
    scatterk<<<(E + 3) / 4, 256, 0, stream>>>(ei, hs, agg, E);
    epiloguek<<<(N + 31) / 32, 256, 0, stream>>>(agg, dinv, x, ab, cb, ga, colsum, N);
    actork<<<(N + 7) / 8, 256, 0, stream>>>(ga, a1W, a1b, a2W, a2b, a3W, a3b, out, pSum, N);
    critick<<<1, 64, 0, stream>>>(colsum, c1W, c1b, c2W, c2b, c3W, c3b, out, N);
    normk<<<(N + 255) / 256, 256, 0, stream>>>(out, pSum, N);
}

// Round 3
// 623.266 us; speedup vs baseline: 2.4769x; 2.4769x over previous
//
#include <hip/hip_runtime.h>
#include <hip/hip_bf16.h>
#include <math.h>

#define C 128

// ---------------- init: zero counters ----------------
__global__ __launch_bounds__(256) void initk(unsigned* cnt, unsigned* fill, float* colsum, float* pSum, int N) {
    int i = blockIdx.x * 256 + threadIdx.x;
    if (i < N) { cnt[i] = 0u; fill[i] = 0u; }
    if (i < 128) colsum[i] = 0.f;
    if (i == 128) pSum[0] = 0.f;
}

// ---------------- degree count (edge_index is int32) ----------------
__global__ __launch_bounds__(256) void countk(const int* __restrict__ ei, unsigned* cnt, int E) {
    int e = blockIdx.x * 256 + threadIdx.x;
    if (e < E) atomicAdd(&cnt[ei[E + e]], 1u);
}

// ---------------- block sums for scan ----------------
__global__ __launch_bounds__(256) void bsumk(const unsigned* __restrict__ cnt, unsigned* bsum, int N) {
    __shared__ unsigned tmp[256];
    int i = blockIdx.x * 256 + threadIdx.x;
    tmp[threadIdx.x] = (i < N) ? cnt[i] : 0u;
    __syncthreads();
    for (int s = 128; s > 0; s >>= 1) {
        if (threadIdx.x < s) tmp[threadIdx.x] += tmp[threadIdx.x + s];
        __syncthreads();
    }
    if (threadIdx.x == 0) bsum[blockIdx.x] = tmp[0];
}

// ---------------- scan of block sums (nb <= 256) ----------------
__global__ void bscank(const unsigned* __restrict__ bsum, unsigned* __restrict__ bbase, int nb) {
    __shared__ unsigned tmp[256];
    int t = threadIdx.x;
    unsigned v = (t < nb) ? bsum[t] : 0u;
    tmp[t] = v;
    __syncthreads();
    for (int off = 1; off < 256; off <<= 1) {
        unsigned add = (t >= off) ? tmp[t - off] : 0u;
        __syncthreads();
        tmp[t] += add;
        __syncthreads();
    }
    if (t < nb) bbase[t] = tmp[t] - v;   // exclusive
}

// ---------------- write rowptr (inclusive scan + block base) ----------------
__global__ __launch_bounds__(256) void writerowk(const unsigned* __restrict__ cnt,
                                                 const unsigned* __restrict__ bbase,
                                                 int* __restrict__ rowptr, int N) {
    __shared__ unsigned tmp[256];
    int b = blockIdx.x, t = threadIdx.x;
    int i = b * 256 + t;
    unsigned v = (i < N) ? cnt[i] : 0u;
    tmp[t] = v;
    __syncthreads();
    for (int off = 1; off < 256; off <<= 1) {
        unsigned add = (t >= off) ? tmp[t - off] : 0u;
        __syncthreads();
        tmp[t] += add;
        __syncthreads();
    }
    if (i < N) rowptr[i + 1] = (int)(bbase[b] + tmp[t]);
    if (i == 0) rowptr[0] = 0;
}

// ---------------- dinv = rsqrt(deg+1) ----------------
__global__ __launch_bounds__(256) void dinvk(const unsigned* __restrict__ cnt, float* __restrict__ dinv, int N) {
    int i = blockIdx.x * 256 + threadIdx.x;
    if (i < N) dinv[i] = rsqrtf((float)(cnt[i] + 1u));
}

// ---------------- fill CSR column array ----------------
__global__ __launch_bounds__(256) void fillk(const int* __restrict__ ei, const int* __restrict__ rowptr,
                                             unsigned* __restrict__ fill, int* __restrict__ col, int E) {
    int e = blockIdx.x * 256 + threadIdx.x;
    if (e < E) {
        int d = ei[E + e];
        int pos = rowptr[d] + (int)atomicAdd(&fill[d], 1u);
        col[pos] = ei[e];
    }
}

// ---------------- fused GEMM: hs[i, y*128 + n] = dinv[i] * (x @ W_y) ----------------
__global__ __launch_bounds__(256) void gemmk(const float* __restrict__ x,
                                             const float* __restrict__ aW,
                                             const float* __restrict__ cW,
                                             const float* __restrict__ dinv,
                                             float* __restrict__ hs, int N) {
    __shared__ float As[32][132];
    __shared__ float Bs[32][132];
    const float* W = (blockIdx.y == 0) ? aW : cW;
    const int colBase = blockIdx.y * 128;
    const int row0 = blockIdx.x * 128;
    const int t = threadIdx.x;
    const int tx = t & 15, ty = t >> 4;
    float acc[8][8] = {};

    for (int k0 = 0; k0 < C; k0 += 32) {
        for (int i = 0; i < 4; ++i) {
            int v = t + i * 256;
            int kq = v & 7, row = v >> 3;
            int grow = row0 + row;
            float4 f = make_float4(0.f, 0.f, 0.f, 0.f);
            if (grow < N) f = *(const float4*)&x[(size_t)grow * C + k0 + kq * 4];
            As[kq * 4 + 0][row] = f.x;
            As[kq * 4 + 1][row] = f.y;
            As[kq * 4 + 2][row] = f.z;
            As[kq * 4 + 3][row] = f.w;
        }
        for (int i = 0; i < 4; ++i) {
            int v = t + i * 256;
            int nq = v & 31, kk = v >> 5;
            *(float4*)&Bs[kk][nq * 4] = *(const float4*)&W[(size_t)(k0 + kk) * C + nq * 4];
        }
        __syncthreads();
        for (int kk = 0; kk < 32; ++kk) {
            float a[8], b[8];
            *(float4*)&a[0] = *(float4*)&As[kk][ty * 8];
            *(float4*)&a[4] = *(float4*)&As[kk][ty * 8 + 4];
            *(float4*)&b[0] = *(float4*)&Bs[kk][tx * 8];
            *(float4*)&b[4] = *(float4*)&Bs[kk][tx * 8 + 4];
#pragma unroll
            for (int m = 0; m < 8; ++m)
#pragma unroll
                for (int n = 0; n < 8; ++n) acc[m][n] += a[m] * b[n];
        }
        __syncthreads();
    }
    for (int m = 0; m < 8; ++m) {
        int grow = row0 + ty * 8 + m;
        if (grow >= N) break;
        float dv = dinv[grow];
        float4 v0, v1;
        v0.x = acc[m][0] * dv; v0.y = acc[m][1] * dv; v0.z = acc[m][2] * dv; v0.w = acc[m][3] * dv;
        v1.x = acc[m][4] * dv; v1.y = acc[m][5] * dv; v1.z = acc[m][6] * dv; v1.w = acc[m][7] * dv;
        size_t base = (size_t)grow * 256 + colBase + tx * 8;
        *(float4*)&hs[base] = v0;
        *(float4*)&hs[base + 4] = v1;
    }
}

// ---------------- CSR gather + fused epilogue ----------------
// block = 1 destination node, 256 threads (1 feature each).
// gag[d][0:128]  = relu(dinv[d]*acc_a + ab) + x[d]   (actor input)
// gag[d][128:256]= relu(dinv[d]*acc_c + cb) + x[d]   (critic rows, later column-summed)
__global__ __launch_bounds__(256) void gatherk(const int* __restrict__ col,
                                               const int* __restrict__ rowptr,
                                               const float* __restrict__ hs,
                                               const float* __restrict__ dinv,
                                               const float* __restrict__ x,
                                               const float* __restrict__ ab,
                                               const float* __restrict__ cb,
                                               float* __restrict__ gag, int N) {
    __shared__ int snb[256];
    int d = blockIdx.x, t = threadIdx.x;
    int beg = rowptr[d], end = rowptr[d + 1];
    float acc = hs[(size_t)d * 256 + t];   // self-loop term (hs already dinv-scaled)
    for (int c = beg; c < end; c += 256) {
        int idx = c + t;
        if (idx < end) snb[t] = col[idx];
        __syncthreads();
        int n = end - c; if (n > 256) n = 256;
        int j = 0;
        for (; j + 3 < n; j += 4) {
            float v0 = hs[(size_t)snb[j] * 256 + t];
            float v1 = hs[(size_t)snb[j + 1] * 256 + t];
            float v2 = hs[(size_t)snb[j + 2] * 256 + t];
            float v3 = hs[(size_t)snb[j + 3] * 256 + t];
            acc += v0 + v1 + v2 + v3;
        }
        for (; j < n; ++j) acc += hs[(size_t)snb[j] * 256 + t];
        __syncthreads();
    }
    float bias = (t < 128) ? ab[t] : cb[t & 127];
    float r = fmaxf(dinv[d] * acc + bias, 0.f) + x[(size_t)d * C + (t & 127)];
    gag[(size_t)d * 256 + t] = r;
}

// ---------------- critic column sum over gag[:,128:256] ----------------
__global__ __launch_bounds__(128) void colsumk(const float* __restrict__ gag, float* __restrict__ colsum, int N) {
    int t = threadIdx.x;
    int r0 = blockIdx.x * 256;
    float acc = 0.f;
    for (int r = 0; r < 256; ++r) {
        int i = r0 + r;
        if (i >= N) break;
        acc += gag[(size_t)i * 256 + 128 + t];
    }
    atomicAdd(&colsum[t], acc);
}

__device__ inline float softplusf(float v) {
    return (v > 20.f) ? v : log1pf(expf(v));
}

// ---------------- actor MLP: 8 nodes per block ----------------
__global__ __launch_bounds__(256) void actork(const float* __restrict__ gag,
                                              const float* __restrict__ a1W, const float* __restrict__ a1b,
                                              const float* __restrict__ a2W, const float* __restrict__ a2b,
                                              const float* __restrict__ a3W, const float* __restrict__ a3b,
                                              float* __restrict__ out, float* __restrict__ pSum, int N) {
    __shared__ float sga[8][132];
    __shared__ float sh1[8][33];
    __shared__ float sh2[8][33];
    __shared__ float sp[8];
    int t = threadIdx.x;
    int i0 = blockIdx.x * 8;
    for (int i = 0; i < 4; ++i) {
        int v = t + i * 256;
        int r = v >> 7, c = v & 127;
        int node = i0 + r;
        sga[r][c] = (node < N) ? gag[(size_t)node * 256 + c] : 0.f;
    }
    __syncthreads();
    int n = t >> 5, o = t & 31;
    float acc = a1b[o];
#pragma unroll 8
    for (int k = 0; k < 128; ++k) acc += sga[n][k] * a1W[k * 32 + o];
    sh1[n][o] = fmaxf(acc, 0.f);
    __syncthreads();
    acc = a2b[o];
#pragma unroll
    for (int k = 0; k < 32; ++k) acc += sh1[n][k] * a2W[k * 32 + o];
    sh2[n][o] = fmaxf(acc, 0.f);
    __syncthreads();
    if (o < 2) {
        float a = a3b[o];
#pragma unroll
        for (int k = 0; k < 32; ++k) a += sh2[n][k] * a3W[k * 2 + o];
        int node = i0 + n;
        if (node < N) {
            float spv = softplusf(a);
            if (o == 0) out[node] = spv + 1e-20f;
            else { out[(size_t)N + 2 + node] = spv; sp[n] = spv; }
        } else if (o == 1) sp[n] = 0.f;
    }
    __syncthreads();
    if (t == 0) {
        float s = 0.f;
        for (int j = 0; j < 8; ++j) s += sp[j];
        atomicAdd(pSum, s);
    }
}

// ---------------- critic head ----------------
__global__ void critick(const float* __restrict__ colsum,
                        const float* __restrict__ c1W, const float* __restrict__ c1b,
                        const float* __restrict__ c2W, const float* __restrict__ c2b,
                        const float* __restrict__ c3W, const float* __restrict__ c3b,
                        float* __restrict__ out, int N) {
    __shared__ float s1[32], s2[32];
    int t = threadIdx.x;
    if (t < 32) {
        float acc = c1b[t];
        for (int k = 0; k < 128; ++k) acc += colsum[k] * c1W[k * 32 + t];
        s1[t] = fmaxf(acc, 0.f);
    }
    __syncthreads();
    if (t < 32) {
        float acc = c2b[t];
        for (int k = 0; k < 32; ++k) acc += s1[k] * c2W[k * 32 + t];
        s2[t] = fmaxf(acc, 0.f);
    }
    __syncthreads();
    if (t < 2) {
        float acc = c3b[t];
        for (int k = 0; k < 32; ++k) acc += s2[k] * c3W[k * 2 + t];
        out[(size_t)N + t] = acc;
    }
}

// ---------------- normalize probs ----------------
__global__ __launch_bounds__(256) void normk(float* __restrict__ out, const float* __restrict__ pSum, int N) {
    int i = blockIdx.x * 256 + threadIdx.x;
    if (i < N) out[(size_t)N + 2 + i] /= pSum[0];
}

extern "C" void kernel_launch(void* const* d_in, const int* in_sizes, int n_in,
                              void* d_out, int out_size, void* d_ws, size_t ws_size,
                              hipStream_t stream) {
    const float* x   = (const float*)d_in[0];
    const int* ei    = (const int*)d_in[1];
    const float* aW  = (const float*)d_in[2];
    const float* ab  = (const float*)d_in[3];
    const float* a1W = (const float*)d_in[4];
    const float* a1b = (const float*)d_in[5];
    const float* a2W = (const float*)d_in[6];
    const float* a2b = (const float*)d_in[7];
    const float* a3W = (const float*)d_in[8];
    const float* a3b = (const float*)d_in[9];
    const float* cW  = (const float*)d_in[10];
    const float* cb  = (const float*)d_in[11];
    const float* c1W = (const float*)d_in[12];
    const float* c1b = (const float*)d_in[13];
    const float* c2W = (const float*)d_in[14];
    const float* c2b = (const float*)d_in[15];
    const float* c3W = (const float*)d_in[16];
    const float* c3b = (const float*)d_in[17];

    const int N = in_sizes[0] / C;
    const int E = in_sizes[1] / 2;
    const int nb = (N + 255) / 256;
    float* out = (float*)d_out;

    char* ws = (char*)d_ws;
    size_t off = 0;
    auto alloc = [&](size_t bytes) {
        size_t o = off;
        off = (off + bytes + 255) & ~(size_t)255;
        return (void*)(ws + o);
    };
    unsigned* cnt   = (unsigned*)alloc((size_t)N * 4);
    float* dinv     = (float*)alloc((size_t)N * 4);
    unsigned* fill  = (unsigned*)alloc((size_t)N * 4);
    int* rowptr     = (int*)alloc((size_t)(N + 1) * 4);
    unsigned* bsum  = (unsigned*)alloc(256 * 4);
    unsigned* bbase = (unsigned*)alloc(256 * 4);
    int* colidx     = (int*)alloc((size_t)E * 4);
    float* hs       = (float*)alloc((size_t)N * 256 * 4);
    float* gag      = (float*)alloc((size_t)N * 256 * 4);
    float* colsum   = (float*)alloc(128 * 4);
    float* pSum     = (float*)alloc(4);

    initk<<<nb, 256, 0, stream>>>(cnt, fill, colsum, pSum, N);
    countk<<<(E + 255) / 256, 256, 0, stream>>>(ei, cnt, E);
    bsumk<<<nb, 256, 0, stream>>>(cnt, bsum, N);
    bscank<<<1, 256, 0, stream>>>(bsum, bbase, nb);
    writerowk<<<nb, 256, 0, stream>>>(cnt, bbase, rowptr, N);
    dinvk<<<nb, 256, 0, stream>>>(cnt, dinv, N);
    fillk<<<(E + 255) / 256, 256, 0, stream>>>(ei, rowptr, fill, colidx, E);
    gemmk<<<dim3((N + 127) / 128, 2), 256, 0, stream>>>(x, aW, cW, dinv, hs, N);
    gatherk<<<N, 256, 0, stream>>>(colidx, rowptr, hs, dinv, x, ab, cb, gag, N);
    colsumk<<<nb, 128, 0, stream>>>(gag, colsum, N);
    actork<<<(N + 7) / 8, 256, 0, stream>>>(gag, a1W, a1b, a2W, a2b, a3W, a3b, out, pSum, N);
    critick<<<1, 64, 0, stream>>>(colsum, c1W, c1b, c2W, c2b, c3W, c3b, out, N);
    normk<<<(N + 255) / 256, 256, 0, stream>>>(out, pSum, N);
}

// Round 4
// 514.087 us; speedup vs baseline: 3.0029x; 1.2124x over previous
//
#include <hip/hip_runtime.h>
#include <hip/hip_bf16.h>
#include <hip/hip_fp16.h>
#include <math.h>

#define C 128

__device__ inline float4 h4_to_f4(uint2 u) {
    __half2 p0 = *(__half2*)&u.x;
    __half2 p1 = *(__half2*)&u.y;
    float2 f0 = __half22float2(p0), f1 = __half22float2(p1);
    return make_float4(f0.x, f0.y, f1.x, f1.y);
}

// ---------------- init ----------------
__global__ __launch_bounds__(256) void initk(unsigned* cnt, unsigned* fill, float* colsum, float* pSum, int N) {
    int i = blockIdx.x * 256 + threadIdx.x;
    if (i < N) { cnt[i] = 0u; fill[i] = 0u; }
    if (i < 128) colsum[i] = 0.f;
    if (i == 128) pSum[0] = 0.f;
}

// ---------------- degree count ----------------
__global__ __launch_bounds__(256) void countk(const int* __restrict__ ei, unsigned* cnt, int E) {
    int e = blockIdx.x * 256 + threadIdx.x;
    if (e < E) atomicAdd(&cnt[ei[E + e]], 1u);
}

// ---------------- block sums for scan ----------------
__global__ __launch_bounds__(256) void bsumk(const unsigned* __restrict__ cnt, unsigned* bsum, int N) {
    __shared__ unsigned tmp[256];
    int i = blockIdx.x * 256 + threadIdx.x;
    tmp[threadIdx.x] = (i < N) ? cnt[i] : 0u;
    __syncthreads();
    for (int s = 128; s > 0; s >>= 1) {
        if (threadIdx.x < s) tmp[threadIdx.x] += tmp[threadIdx.x + s];
        __syncthreads();
    }
    if (threadIdx.x == 0) bsum[blockIdx.x] = tmp[0];
}

// ---------------- scan of block sums (nb <= 256) ----------------
__global__ void bscank(const unsigned* __restrict__ bsum, unsigned* __restrict__ bbase, int nb) {
    __shared__ unsigned tmp[256];
    int t = threadIdx.x;
    unsigned v = (t < nb) ? bsum[t] : 0u;
    tmp[t] = v;
    __syncthreads();
    for (int off = 1; off < 256; off <<= 1) {
        unsigned add = (t >= off) ? tmp[t - off] : 0u;
        __syncthreads();
        tmp[t] += add;
        __syncthreads();
    }
    if (t < nb) bbase[t] = tmp[t] - v;   // exclusive
}

// ---------------- rowptr ----------------
__global__ __launch_bounds__(256) void writerowk(const unsigned* __restrict__ cnt,
                                                 const unsigned* __restrict__ bbase,
                                                 int* __restrict__ rowptr, int N) {
    __shared__ unsigned tmp[256];
    int b = blockIdx.x, t = threadIdx.x;
    int i = b * 256 + t;
    unsigned v = (i < N) ? cnt[i] : 0u;
    tmp[t] = v;
    __syncthreads();
    for (int off = 1; off < 256; off <<= 1) {
        unsigned add = (t >= off) ? tmp[t - off] : 0u;
        __syncthreads();
        tmp[t] += add;
        __syncthreads();
    }
    if (i < N) rowptr[i + 1] = (int)(bbase[b] + tmp[t]);
    if (i == 0) rowptr[0] = 0;
}

// ---------------- dinv ----------------
__global__ __launch_bounds__(256) void dinvk(const unsigned* __restrict__ cnt, float* __restrict__ dinv, int N) {
    int i = blockIdx.x * 256 + threadIdx.x;
    if (i < N) dinv[i] = rsqrtf((float)(cnt[i] + 1u));
}

// ---------------- fill CSR col ----------------
__global__ __launch_bounds__(256) void fillk(const int* __restrict__ ei, const int* __restrict__ rowptr,
                                             unsigned* __restrict__ fill, int* __restrict__ col, int E) {
    int e = blockIdx.x * 256 + threadIdx.x;
    if (e < E) {
        int d = ei[E + e];
        int pos = rowptr[d] + (int)atomicAdd(&fill[d], 1u);
        col[pos] = ei[e];
    }
}

// ---------------- fused GEMM -> fp16 hs: hs[i, y*128+n] = dinv[i]*(x@W_y) ----------------
__global__ __launch_bounds__(256) void gemmk(const float* __restrict__ x,
                                             const float* __restrict__ aW,
                                             const float* __restrict__ cW,
                                             const float* __restrict__ dinv,
                                             __half* __restrict__ hs, int N) {
    __shared__ float As[32][132];
    __shared__ float Bs[32][132];
    const float* W = (blockIdx.y == 0) ? aW : cW;
    const int colBase = blockIdx.y * 128;
    const int row0 = blockIdx.x * 128;
    const int t = threadIdx.x;
    const int tx = t & 15, ty = t >> 4;
    float acc[8][8] = {};

    for (int k0 = 0; k0 < C; k0 += 32) {
        for (int i = 0; i < 4; ++i) {
            int v = t + i * 256;
            int kq = v & 7, row = v >> 3;
            int grow = row0 + row;
            float4 f = make_float4(0.f, 0.f, 0.f, 0.f);
            if (grow < N) f = *(const float4*)&x[(size_t)grow * C + k0 + kq * 4];
            As[kq * 4 + 0][row] = f.x;
            As[kq * 4 + 1][row] = f.y;
            As[kq * 4 + 2][row] = f.z;
            As[kq * 4 + 3][row] = f.w;
        }
        for (int i = 0; i < 4; ++i) {
            int v = t + i * 256;
            int nq = v & 31, kk = v >> 5;
            *(float4*)&Bs[kk][nq * 4] = *(const float4*)&W[(size_t)(k0 + kk) * C + nq * 4];
        }
        __syncthreads();
        for (int kk = 0; kk < 32; ++kk) {
            float a[8], b[8];
            *(float4*)&a[0] = *(float4*)&As[kk][ty * 8];
            *(float4*)&a[4] = *(float4*)&As[kk][ty * 8 + 4];
            *(float4*)&b[0] = *(float4*)&Bs[kk][tx * 8];
            *(float4*)&b[4] = *(float4*)&Bs[kk][tx * 8 + 4];
#pragma unroll
            for (int m = 0; m < 8; ++m)
#pragma unroll
                for (int n = 0; n < 8; ++n) acc[m][n] += a[m] * b[n];
        }
        __syncthreads();
    }
    for (int m = 0; m < 8; ++m) {
        int grow = row0 + ty * 8 + m;
        if (grow >= N) break;
        float dv = dinv[grow];
        __half2 h[4];
        h[0] = __floats2half2_rn(acc[m][0] * dv, acc[m][1] * dv);
        h[1] = __floats2half2_rn(acc[m][2] * dv, acc[m][3] * dv);
        h[2] = __floats2half2_rn(acc[m][4] * dv, acc[m][5] * dv);
        h[3] = __floats2half2_rn(acc[m][6] * dv, acc[m][7] * dv);
        size_t base = (size_t)grow * 256 + colBase + tx * 8;
        *(uint4*)&hs[base] = *(uint4*)&h[0];
    }
}

// ---------------- CSR gather, one wave per node ----------------
// lane l owns features 4l..4l+3 (fp16 row = 512B, 8B per lane per neighbor).
// gag[d][0:128]=relu(dinv*acc_a+ab)+x[d]; gag[d][128:256]=relu(dinv*acc_c+cb)+x[d]  (fp16)
__global__ __launch_bounds__(256) void gatherk(const int* __restrict__ col,
                                               const int* __restrict__ rowptr,
                                               const __half* __restrict__ hs,
                                               const float* __restrict__ dinv,
                                               const float* __restrict__ x,
                                               const float* __restrict__ ab,
                                               const float* __restrict__ cb,
                                               __half* __restrict__ gag, int N) {
    __shared__ int snb[4][64];
    int wid = threadIdx.x >> 6;
    int lane = threadIdx.x & 63;
    int d = blockIdx.x * 4 + wid;
    if (d >= N) return;
    int beg = rowptr[d], end = rowptr[d + 1];
    int f = lane * 4;

    // self-loop term
    float4 s = h4_to_f4(*(const uint2*)&hs[(size_t)d * 256 + f]);
    float a0 = s.x, a1 = s.y, a2 = s.z, a3 = s.w;

    for (int c = beg; c < end; c += 64) {
        if (c + lane < end) snb[wid][lane] = col[c + lane];
        int n = end - c; if (n > 64) n = 64;
        int j = 0;
        for (; j + 3 < n; j += 4) {
            size_t i0 = (size_t)snb[wid][j] * 256 + f;
            size_t i1 = (size_t)snb[wid][j + 1] * 256 + f;
            size_t i2 = (size_t)snb[wid][j + 2] * 256 + f;
            size_t i3 = (size_t)snb[wid][j + 3] * 256 + f;
            float4 v0 = h4_to_f4(*(const uint2*)&hs[i0]);
            float4 v1 = h4_to_f4(*(const uint2*)&hs[i1]);
            float4 v2 = h4_to_f4(*(const uint2*)&hs[i2]);
            float4 v3 = h4_to_f4(*(const uint2*)&hs[i3]);
            a0 += v0.x + v1.x + v2.x + v3.x;
            a1 += v0.y + v1.y + v2.y + v3.y;
            a2 += v0.z + v1.z + v2.z + v3.z;
            a3 += v0.w + v1.w + v2.w + v3.w;
        }
        for (; j < n; ++j) {
            float4 v = h4_to_f4(*(const uint2*)&hs[(size_t)snb[wid][j] * 256 + f]);
            a0 += v.x; a1 += v.y; a2 += v.z; a3 += v.w;
        }
    }

    float dv = dinv[d];
    int xo = f & 127;
    float4 xv = *(const float4*)&x[(size_t)d * C + xo];
    const float* bias = (f < 128) ? (ab + f) : (cb + f - 128);
    float4 bv = *(const float4*)bias;
    float r0 = fmaxf(dv * a0 + bv.x, 0.f) + xv.x;
    float r1 = fmaxf(dv * a1 + bv.y, 0.f) + xv.y;
    float r2 = fmaxf(dv * a2 + bv.z, 0.f) + xv.z;
    float r3 = fmaxf(dv * a3 + bv.w, 0.f) + xv.w;
    __half2 h0 = __floats2half2_rn(r0, r1);
    __half2 h1 = __floats2half2_rn(r2, r3);
    uint2 u; u.x = *(unsigned*)&h0; u.y = *(unsigned*)&h1;
    *(uint2*)&gag[(size_t)d * 256 + f] = u;
}

// ---------------- critic column sum over gag[:,128:256] (fp16) ----------------
// block = 256 threads = 4 row-groups x 64 lanes; lane owns feature pair 2*lane.
__global__ __launch_bounds__(256) void colsumk(const __half* __restrict__ gag, float* __restrict__ colsum, int N) {
    int t = threadIdx.x;
    int lane = t & 63, rg = t >> 6;
    int fp = 128 + lane * 2;
    float sx = 0.f, sy = 0.f;
    int r0 = blockIdx.x * 1024;
    int rend = r0 + 1024; if (rend > N) rend = N;
    for (int i = r0 + rg; i < rend; i += 4) {
        unsigned u = *(const unsigned*)&gag[(size_t)i * 256 + fp];
        __half2 h = *(__half2*)&u;
        float2 fv = __half22float2(h);
        sx += fv.x; sy += fv.y;
    }
    atomicAdd(&colsum[lane * 2], sx);
    atomicAdd(&colsum[lane * 2 + 1], sy);
}

__device__ inline float softplusf(float v) {
    return (v > 20.f) ? v : log1pf(expf(v));
}

// ---------------- actor MLP: 8 nodes per block (fp16 input) ----------------
__global__ __launch_bounds__(256) void actork(const __half* __restrict__ gag,
                                              const float* __restrict__ a1W, const float* __restrict__ a1b,
                                              const float* __restrict__ a2W, const float* __restrict__ a2b,
                                              const float* __restrict__ a3W, const float* __restrict__ a3b,
                                              float* __restrict__ out, float* __restrict__ pSum, int N) {
    __shared__ float sga[8][132];
    __shared__ float sh1[8][33];
    __shared__ float sh2[8][33];
    __shared__ float sp[8];
    int t = threadIdx.x;
    int i0 = blockIdx.x * 8;
    for (int i = 0; i < 2; ++i) {
        int v = t + i * 256;              // 0..511 -> 8 nodes x 64 half2
        int r = v >> 6, cp = v & 63;
        int node = i0 + r;
        float2 fv = make_float2(0.f, 0.f);
        if (node < N) {
            unsigned u = *(const unsigned*)&gag[(size_t)node * 256 + cp * 2];
            fv = __half22float2(*(__half2*)&u);
        }
        sga[r][cp * 2] = fv.x;
        sga[r][cp * 2 + 1] = fv.y;
    }
    __syncthreads();
    int n = t >> 5, o = t & 31;
    float acc = a1b[o];
#pragma unroll 8
    for (int k = 0; k < 128; ++k) acc += sga[n][k] * a1W[k * 32 + o];
    sh1[n][o] = fmaxf(acc, 0.f);
    __syncthreads();
    acc = a2b[o];
#pragma unroll
    for (int k = 0; k < 32; ++k) acc += sh1[n][k] * a2W[k * 32 + o];
    sh2[n][o] = fmaxf(acc, 0.f);
    __syncthreads();
    if (o < 2) {
        float a = a3b[o];
#pragma unroll
        for (int k = 0; k < 32; ++k) a += sh2[n][k] * a3W[k * 2 + o];
        int node = i0 + n;
        if (node < N) {
            float spv = softplusf(a);
            if (o == 0) out[node] = spv + 1e-20f;
            else { out[(size_t)N + 2 + node] = spv; sp[n] = spv; }
        } else if (o == 1) sp[n] = 0.f;
    }
    __syncthreads();
    if (t == 0) {
        float s = 0.f;
        for (int j = 0; j < 8; ++j) s += sp[j];
        atomicAdd(pSum, s);
    }
}

// ---------------- critic head ----------------
__global__ void critick(const float* __restrict__ colsum,
                        const float* __restrict__ c1W, const float* __restrict__ c1b,
                        const float* __restrict__ c2W, const float* __restrict__ c2b,
                        const float* __restrict__ c3W, const float* __restrict__ c3b,
                        float* __restrict__ out, int N) {
    __shared__ float s1[32], s2[32];
    int t = threadIdx.x;
    if (t < 32) {
        float acc = c1b[t];
        for (int k = 0; k < 128; ++k) acc += colsum[k] * c1W[k * 32 + t];
        s1[t] = fmaxf(acc, 0.f);
    }
    __syncthreads();
    if (t < 32) {
        float acc = c2b[t];
        for (int k = 0; k < 32; ++k) acc += s1[k] * c2W[k * 32 + t];
        s2[t] = fmaxf(acc, 0.f);
    }
    __syncthreads();
    if (t < 2) {
        float acc = c3b[t];
        for (int k = 0; k < 32; ++k) acc += s2[k] * c3W[k * 2 + t];
        out[(size_t)N + t] = acc;
    }
}

// ---------------- normalize probs ----------------
__global__ __launch_bounds__(256) void normk(float* __restrict__ out, const float* __restrict__ pSum, int N) {
    int i = blockIdx.x * 256 + threadIdx.x;
    if (i < N) out[(size_t)N + 2 + i] /= pSum[0];
}

extern "C" void kernel_launch(void* const* d_in, const int* in_sizes, int n_in,
                              void* d_out, int out_size, void* d_ws, size_t ws_size,
                              hipStream_t stream) {
    const float* x   = (const float*)d_in[0];
    const int* ei    = (const int*)d_in[1];
    const float* aW  = (const float*)d_in[2];
    const float* ab  = (const float*)d_in[3];
    const float* a1W = (const float*)d_in[4];
    const float* a1b = (const float*)d_in[5];
    const float* a2W = (const float*)d_in[6];
    const float* a2b = (const float*)d_in[7];
    const float* a3W = (const float*)d_in[8];
    const float* a3b = (const float*)d_in[9];
    const float* cW  = (const float*)d_in[10];
    const float* cb  = (const float*)d_in[11];
    const float* c1W = (const float*)d_in[12];
    const float* c1b = (const float*)d_in[13];
    const float* c2W = (const float*)d_in[14];
    const float* c2b = (const float*)d_in[15];
    const float* c3W = (const float*)d_in[16];
    const float* c3b = (const float*)d_in[17];

    const int N = in_sizes[0] / C;
    const int E = in_sizes[1] / 2;
    const int nb = (N + 255) / 256;
    float* out = (float*)d_out;

    char* ws = (char*)d_ws;
    size_t off = 0;
    auto alloc = [&](size_t bytes) {
        size_t o = off;
        off = (off + bytes + 255) & ~(size_t)255;
        return (void*)(ws + o);
    };
    unsigned* cnt   = (unsigned*)alloc((size_t)N * 4);
    float* dinv     = (float*)alloc((size_t)N * 4);
    unsigned* fill  = (unsigned*)alloc((size_t)N * 4);
    int* rowptr     = (int*)alloc((size_t)(N + 1) * 4);
    unsigned* bsum  = (unsigned*)alloc(256 * 4);
    unsigned* bbase = (unsigned*)alloc(256 * 4);
    int* colidx     = (int*)alloc((size_t)E * 4);
    __half* hs      = (__half*)alloc((size_t)N * 256 * 2);
    __half* gag     = (__half*)alloc((size_t)N * 256 * 2);
    float* colsum   = (float*)alloc(128 * 4);
    float* pSum     = (float*)alloc(4);

    initk<<<nb, 256, 0, stream>>>(cnt, fill, colsum, pSum, N);
    countk<<<(E + 255) / 256, 256, 0, stream>>>(ei, cnt, E);
    bsumk<<<nb, 256, 0, stream>>>(cnt, bsum, N);
    bscank<<<1, 256, 0, stream>>>(bsum, bbase, nb);
    writerowk<<<nb, 256, 0, stream>>>(cnt, bbase, rowptr, N);
    dinvk<<<nb, 256, 0, stream>>>(cnt, dinv, N);
    fillk<<<(E + 255) / 256, 256, 0, stream>>>(ei, rowptr, fill, colidx, E);
    gemmk<<<dim3((N + 127) / 128, 2), 256, 0, stream>>>(x, aW, cW, dinv, hs, N);
    gatherk<<<(N + 3) / 4, 256, 0, stream>>>(colidx, rowptr, hs, dinv, x, ab, cb, gag, N);
    colsumk<<<(N + 1023) / 1024, 256, 0, stream>>>(gag, colsum, N);
    actork<<<(N + 7) / 8, 256, 0, stream>>>(gag, a1W, a1b, a2W, a2b, a3W, a3b, out, pSum, N);
    critick<<<1, 64, 0, stream>>>(colsum, c1W, c1b, c2W, c2b, c3W, c3b, out, N);
    normk<<<(N + 255) / 256, 256, 0, stream>>>(out, pSum, N);
}